// Round 12
// baseline (185.818 us; speedup 1.0000x reference)
//
#include <hip/hip_runtime.h>
#include <hip/hip_bf16.h>

typedef __hip_bfloat16 bf16;
typedef __attribute__((ext_vector_type(8))) short bf16x8;
typedef __attribute__((ext_vector_type(4))) float f32x4;

#define N_NODE 20000
#define D      128
#define NEDGE  300000
#define NROW2  (2 * N_NODE)          // merged CSR rows: drug(rev) | disease(ind+dd)
#define NBIN   ((NROW2 + 255) >> 8)  // 157 bins of 256 rows
#define NB3    220                   // hist / binscat blocks (220*4096 >= 900000)
#define CHUNK  4096
#define GBE    ((N_NODE + 63) / 64)  // gemm blocks per etype = 313
#define GEMMB  (3 * GBE)             // 939
#define WT_LD  132                   // padded LDS leading dim (bank-conflict-free)

__device__ __forceinline__ short f2bs(float x) {
    bf16 h = __float2bfloat16(x);
    short s; __builtin_memcpy(&s, &h, 2); return s;
}

// ================================================================ K_A
// Fused: blocks [0, GEMMB) = 3 MFMA GEMMs + projections; blocks
// [GEMMB, GEMMB+NB3) = per-block partial bin histograms (no atomics, no init).
// Merged-row mapping: row = (t==0) ? dst : N_NODE + dst  (ind and dd share
// disease rows; etype recoverable from gsrc = t*N_NODE+src).
union SharedA {
    short Wt[D * WT_LD];   // 33,792 B (gemm branch)
    int   h[NBIN];         //    628 B (hist branch)
};

__global__ __launch_bounds__(256) void gemm_and_count(
    const float* __restrict__ feat_drug, const float* __restrict__ feat_dis,
    const float* __restrict__ W_ind, const float* __restrict__ b_ind,
    const float* __restrict__ a_ind,
    const float* __restrict__ W_rev, const float* __restrict__ b_rev,
    const float* __restrict__ a_rev,
    const float* __restrict__ W_dd, const float* __restrict__ b_dd,
    const float* __restrict__ a_dd,
    const int* __restrict__ dst_rev, const int* __restrict__ dst_ind,
    const int* __restrict__ dst_dd,
    bf16* __restrict__ Wh_all, float* __restrict__ el_all,
    float* __restrict__ er_all, int* __restrict__ bin_part) {
    __shared__ SharedA su;
    const int tid = threadIdx.x;

    if (blockIdx.x >= GEMMB) {
        // ---------- bin histogram branch ----------
        const int blk = blockIdx.x - GEMMB;
        for (int i = tid; i < NBIN; i += 256) su.h[i] = 0;
        __syncthreads();
        const int base = blk * CHUNK;
        const int lim = min(base + CHUNK, 3 * NEDGE);
        for (int i = base + tid; i < lim; i += 256) {
            const int t = (i >= 2 * NEDGE) ? 2 : (i >= NEDGE ? 1 : 0);
            const int e = i - t * NEDGE;
            const int d = (t == 0 ? dst_rev : (t == 1 ? dst_ind : dst_dd))[e];
            const int row = (t == 0) ? d : (N_NODE + d);
            atomicAdd(&su.h[row >> 8], 1);
        }
        __syncthreads();
        for (int i = tid; i < NBIN; i += 256)
            bin_part[blk * NBIN + i] = su.h[i];
        return;
    }

    // ---------- GEMM branch ----------
    const int t  = blockIdx.x / GBE;
    const int mb = blockIdx.x - t * GBE;

    const float *feat, *W, *bias, *va, *vb;
    float *el_o, *er_o;
    if (t == 0)      { feat = feat_dis;  W = W_rev; bias = b_rev; va = a_rev; vb = a_ind + D; el_o = el_all;              er_o = er_all + N_NODE; }
    else if (t == 1) { feat = feat_drug; W = W_ind; bias = b_ind; va = a_ind; vb = a_rev + D; el_o = el_all + N_NODE;     er_o = er_all; }
    else             { feat = feat_dis;  W = W_dd;  bias = b_dd;  va = a_dd;  vb = a_dd + D;  el_o = el_all + 2 * N_NODE; er_o = er_all + 2 * N_NODE; }
    bf16* wh_o = Wh_all + (size_t)t * N_NODE * D;

    for (int i = tid * 4; i < D * D; i += 1024) {
        const float4 wv = *(const float4*)(W + i);
        const int k = i >> 7, n = i & (D - 1);
        su.Wt[(n + 0) * WT_LD + k] = f2bs(wv.x);
        su.Wt[(n + 1) * WT_LD + k] = f2bs(wv.y);
        su.Wt[(n + 2) * WT_LD + k] = f2bs(wv.z);
        su.Wt[(n + 3) * WT_LD + k] = f2bs(wv.w);
    }
    __syncthreads();

    const int wave = tid >> 6, lane = tid & 63;
    const int q = lane >> 4, nn = lane & 15;
    const int row0 = mb * 64 + wave * 16;
    const int arow = min(row0 + nn, N_NODE - 1);

    f32x4 acc[8];
#pragma unroll
    for (int nt = 0; nt < 8; ++nt) acc[nt] = (f32x4){0.f, 0.f, 0.f, 0.f};

#pragma unroll
    for (int ks = 0; ks < 4; ++ks) {
        const float* ap = feat + (size_t)arow * D + ks * 32 + q * 8;
        const float4 fa = *(const float4*)ap;
        const float4 fb = *(const float4*)(ap + 4);
        bf16x8 afrag;
        afrag[0] = f2bs(fa.x); afrag[1] = f2bs(fa.y);
        afrag[2] = f2bs(fa.z); afrag[3] = f2bs(fa.w);
        afrag[4] = f2bs(fb.x); afrag[5] = f2bs(fb.y);
        afrag[6] = f2bs(fb.z); afrag[7] = f2bs(fb.w);
#pragma unroll
        for (int nt = 0; nt < 8; ++nt) {
            const bf16x8 bfrag =
                *(const bf16x8*)(&su.Wt[(nt * 16 + nn) * WT_LD + ks * 32 + q * 8]);
            acc[nt] = __builtin_amdgcn_mfma_f32_16x16x32_bf16(afrag, bfrag,
                                                              acc[nt], 0, 0, 0);
        }
    }

    float biasv[8], vav[8], vbv[8];
#pragma unroll
    for (int nt = 0; nt < 8; ++nt) {
        const int col = nt * 16 + nn;
        biasv[nt] = bias[col]; vav[nt] = va[col]; vbv[nt] = vb[col];
    }
    float pel[4] = {0.f, 0.f, 0.f, 0.f};
    float per_[4] = {0.f, 0.f, 0.f, 0.f};
    short* whs = (short*)wh_o;
#pragma unroll
    for (int nt = 0; nt < 8; ++nt) {
#pragma unroll
        for (int r = 0; r < 4; ++r) {
            const float c = acc[nt][r] + biasv[nt];
            const int grow = row0 + q * 4 + r;
            if (grow < N_NODE)
                whs[(size_t)grow * D + nt * 16 + nn] = f2bs(c);
            pel[r] = fmaf(c, vav[nt], pel[r]);
            per_[r] = fmaf(c, vbv[nt], per_[r]);
        }
    }
#pragma unroll
    for (int r = 0; r < 4; ++r) {
#pragma unroll
        for (int mask = 1; mask < 16; mask <<= 1) {
            pel[r]  += __shfl_xor(pel[r],  mask, 64);
            per_[r] += __shfl_xor(per_[r], mask, 64);
        }
        const int grow = row0 + q * 4 + r;
        if (nn == 0 && grow < N_NODE) {
            el_o[grow] = pel[r];
            er_o[grow] = per_[r];
        }
    }
}

// ================================================================ K_B binscat
// Deterministic run offsets derived from the partial-hist table (no global
// atomics). Payload u32 = (row16 << 16) | gsrc16; row < 40000, gsrc < 60000.
__global__ __launch_bounds__(256) void binscat(
    const int* __restrict__ src_rev, const int* __restrict__ dst_rev,
    const int* __restrict__ src_ind, const int* __restrict__ dst_ind,
    const int* __restrict__ src_dd,  const int* __restrict__ dst_dd,
    const int* __restrict__ bin_part, int* __restrict__ bin_base_g,
    int* __restrict__ row_ptr, unsigned* __restrict__ bin_buf) {
    __shared__ int runc[NBIN];
    __shared__ int wsum[4];
    const int blk = blockIdx.x;
    const int tid = threadIdx.x;
    const int lane = tid & 63, wave = tid >> 6;

    int tot = 0, pre = 0;
    if (tid < NBIN) {
        for (int j = 0; j < NB3; ++j) {
            const int c = bin_part[j * NBIN + tid];
            tot += c;
            pre += (j < blk) ? c : 0;
        }
    }
    int v = (tid < NBIN) ? tot : 0;
    const int orig = v;
#pragma unroll
    for (int off = 1; off < 64; off <<= 1) {
        int t = __shfl_up(v, off, 64);
        if (lane >= off) v += t;
    }
    if (lane == 63) wsum[wave] = v;
    __syncthreads();
    if (tid == 0) {
        int a = 0;
#pragma unroll
        for (int w = 0; w < 4; ++w) { int t = wsum[w]; wsum[w] = a; a += t; }
    }
    __syncthreads();
    const int excl = wsum[wave] + v - orig;
    if (tid < NBIN) runc[tid] = excl + pre;
    if (blk == 0) {
        if (tid < NBIN) bin_base_g[tid] = excl;
        if (tid == 0) { bin_base_g[NBIN] = 3 * NEDGE; row_ptr[NROW2] = 3 * NEDGE; }
    }
    __syncthreads();

    const int base = blk * CHUNK;
    const int lim = min(base + CHUNK, 3 * NEDGE);
    for (int i = base + tid; i < lim; i += 256) {
        const int t = (i >= 2 * NEDGE) ? 2 : (i >= NEDGE ? 1 : 0);
        const int e = i - t * NEDGE;
        const int sl = (t == 0 ? src_rev : (t == 1 ? src_ind : src_dd))[e];
        const int dl = (t == 0 ? dst_rev : (t == 1 ? dst_ind : dst_dd))[e];
        const int row = (t == 0) ? dl : (N_NODE + dl);
        const int slot = atomicAdd(&runc[row >> 8], 1);
        bin_buf[slot] = ((unsigned)row << 16) | (unsigned)(t * N_NODE + sl);
    }
}

// ================================================================ K_C binsort
__global__ __launch_bounds__(256) void binsort(
    const int* __restrict__ bin_base, const unsigned* __restrict__ bin_buf,
    int* __restrict__ row_ptr, unsigned short* __restrict__ edge_src16) {
    __shared__ int rowcnt[256];
    __shared__ int rankc[256];
    __shared__ int wsum[4];
    const int b = blockIdx.x;
    const int tid = threadIdx.x;
    const int beg = bin_base[b], end = bin_base[b + 1];
    rowcnt[tid] = 0;
    __syncthreads();
    for (int i = beg + tid; i < end; i += 256)
        atomicAdd(&rowcnt[(bin_buf[i] >> 16) & 255], 1);
    __syncthreads();
    const int lane = tid & 63, wave = tid >> 6;
    int v = rowcnt[tid];
    const int orig = v;
#pragma unroll
    for (int off = 1; off < 64; off <<= 1) {
        int t = __shfl_up(v, off, 64);
        if (lane >= off) v += t;
    }
    if (lane == 63) wsum[wave] = v;
    __syncthreads();
    if (tid == 0) {
        int a = 0;
#pragma unroll
        for (int w = 0; w < 4; ++w) { int t = wsum[w]; wsum[w] = a; a += t; }
    }
    __syncthreads();
    const int excl = wsum[wave] + v - orig;
    const int row = b * 256 + tid;
    if (row < NROW2) row_ptr[row] = beg + excl;
    rankc[tid] = beg + excl;
    __syncthreads();
    for (int i = beg + tid; i < end; i += 256) {
        const unsigned u = bin_buf[i];
        const int slot = atomicAdd(&rankc[(u >> 16) & 255], 1);
        edge_src16[slot] = (unsigned short)(u & 0xFFFFu);
    }
}

// ================================================================ K_D gather
// One wave per output row. Merged disease rows carry ind+dd edges; etype is
// derived per edge (gsrc >= 40000 -> dd) so the two softmax normalizers are
// kept independent while sharing one CSR range. Chunk-0 edge meta stays in
// registers (deg <= 64 for virtually every row).
__device__ __forceinline__ void process_chunk(
    int msrc, float mc, int m, int lane,
    const bf16* __restrict__ Wh_all, float& a0, float& a1) {
    int t = 0;
    for (; t + 4 <= m; t += 4) {
        const int s0 = __shfl(msrc, t,     64);
        const int s1 = __shfl(msrc, t + 1, 64);
        const int s2 = __shfl(msrc, t + 2, 64);
        const int s3 = __shfl(msrc, t + 3, 64);
        const float c0 = __shfl(mc, t,     64);
        const float c1 = __shfl(mc, t + 1, 64);
        const float c2 = __shfl(mc, t + 2, 64);
        const float c3 = __shfl(mc, t + 3, 64);
        const unsigned u0 = ((const unsigned*)(Wh_all + (size_t)s0 * D))[lane];
        const unsigned u1 = ((const unsigned*)(Wh_all + (size_t)s1 * D))[lane];
        const unsigned u2 = ((const unsigned*)(Wh_all + (size_t)s2 * D))[lane];
        const unsigned u3 = ((const unsigned*)(Wh_all + (size_t)s3 * D))[lane];
        a0 = fmaf(c0, __uint_as_float(u0 << 16), a0);
        a1 = fmaf(c0, __uint_as_float(u0 & 0xFFFF0000u), a1);
        a0 = fmaf(c1, __uint_as_float(u1 << 16), a0);
        a1 = fmaf(c1, __uint_as_float(u1 & 0xFFFF0000u), a1);
        a0 = fmaf(c2, __uint_as_float(u2 << 16), a0);
        a1 = fmaf(c2, __uint_as_float(u2 & 0xFFFF0000u), a1);
        a0 = fmaf(c3, __uint_as_float(u3 << 16), a0);
        a1 = fmaf(c3, __uint_as_float(u3 & 0xFFFF0000u), a1);
    }
    for (; t < m; ++t) {
        const int s0 = __shfl(msrc, t, 64);
        const float c0 = __shfl(mc, t, 64);
        const unsigned u0 = ((const unsigned*)(Wh_all + (size_t)s0 * D))[lane];
        a0 = fmaf(c0, __uint_as_float(u0 << 16), a0);
        a1 = fmaf(c0, __uint_as_float(u0 & 0xFFFF0000u), a1);
    }
}

__global__ __launch_bounds__(256) void gather_all(
    const int* __restrict__ row_ptr, const unsigned short* __restrict__ edge_src16,
    const float* __restrict__ el_all, const float* __restrict__ er_all,
    const bf16* __restrict__ Wh_all, float* __restrict__ out) {
    const int w = blockIdx.x * (blockDim.x >> 6) + (threadIdx.x >> 6);
    const int lane = threadIdx.x & 63;
    if (w >= NROW2) return;

    const int beg = row_ptr[w], end = row_ptr[w + 1];
    float a0 = 0.f, a1 = 0.f;
    if (end > beg) {
        const float erA = er_all[w];                              // rev or ind
        const float erB = (w >= N_NODE) ? er_all[w + N_NODE] : 0.f; // dd
        const int m0 = min(end - beg, 64);

        // pass 1: lane-owned pe; dual denominators selected by edge etype
        int g0 = 0; float pe0 = 0.f; bool sel0 = false;
        if (lane < m0) {
            g0 = edge_src16[beg + lane];
            sel0 = (g0 >= 2 * N_NODE);
            float v = el_all[g0] + (sel0 ? erB : erA);
            v = v > 0.f ? v : 0.01f * v;
            pe0 = __expf(v);
        }
        float sA = sel0 ? 0.f : pe0;
        float sB = sel0 ? pe0 : 0.f;
        for (int base = beg + 64; base < end; base += 64) {
            const int m = min(end - base, 64);
            if (lane < m) {
                const int g = edge_src16[base + lane];
                const bool sel = (g >= 2 * N_NODE);
                float v = el_all[g] + (sel ? erB : erA);
                v = v > 0.f ? v : 0.01f * v;
                const float pe = __expf(v);
                sA += sel ? 0.f : pe;
                sB += sel ? pe : 0.f;
            }
        }
#pragma unroll
        for (int off = 32; off > 0; off >>= 1) {
            sA += __shfl_down(sA, off, 64);
            sB += __shfl_down(sB, off, 64);
        }
        sA = __shfl(sA, 0, 64);
        sB = __shfl(sB, 0, 64);
        const float invA = (sA > 0.f) ? 1.0f / sA : 0.f;
        const float invB = (sB > 0.f) ? 1.0f / sB : 0.f;

        // pass 2: chunk 0 from registers, rest reloaded (rare)
        const float c0 = pe0 * (sel0 ? invB : invA);
        process_chunk(g0, c0, m0, lane, Wh_all, a0, a1);
        for (int base = beg + 64; base < end; base += 64) {
            const int m = min(end - base, 64);
            int g = 0; float c = 0.f;
            if (lane < m) {
                g = edge_src16[base + lane];
                const bool sel = (g >= 2 * N_NODE);
                float v = el_all[g] + (sel ? erB : erA);
                v = v > 0.f ? v : 0.01f * v;
                c = __expf(v) * (sel ? invB : invA);
            }
            process_chunk(g, c, m, lane, Wh_all, a0, a1);
        }
    }
    ((float2*)(out + (size_t)w * D))[lane] = make_float2(a0, a1);
}

extern "C" void kernel_launch(void* const* d_in, const int* in_sizes, int n_in,
                              void* d_out, int out_size, void* d_ws, size_t ws_size,
                              hipStream_t stream) {
    const float* feat_drug    = (const float*)d_in[0];
    const float* feat_disease = (const float*)d_in[1];
    const float* W_ind = (const float*)d_in[2];
    const float* b_ind = (const float*)d_in[3];
    const float* a_ind = (const float*)d_in[4];
    const float* W_rev = (const float*)d_in[5];
    const float* b_rev = (const float*)d_in[6];
    const float* a_rev = (const float*)d_in[7];
    const float* W_dd  = (const float*)d_in[8];
    const float* b_dd  = (const float*)d_in[9];
    const float* a_dd  = (const float*)d_in[10];
    const int* src_ind = (const int*)d_in[11];
    const int* dst_ind = (const int*)d_in[12];
    const int* src_rev = (const int*)d_in[13];
    const int* dst_rev = (const int*)d_in[14];
    const int* src_dd  = (const int*)d_in[15];
    const int* dst_dd  = (const int*)d_in[16];
    float* out = (float*)d_out;
    (void)in_sizes; (void)n_in; (void)out_size; (void)ws_size;

    // ---- workspace: ~21.5 MB ----
    char* w = (char*)d_ws;
    bf16*  Wh_all   = (bf16*)w;                        // 15,360,000 B [rev|ind|dd]
    float* el_all   = (float*)(w + 15360000);          // 240,000 B
    float* er_all   = (float*)(w + 15600000);          // 240,000 B
    int*   row_ptr  = (int*)(w + 15840000);            // 160,004 -> pad 160,032
    int*   bin_base = (int*)(w + 16000032);            // 632 -> pad 1,024 B
    int*   bin_part = (int*)(w + 16001056);            // 220*157*4 = 138,160 -> pad 138,176
    unsigned* bin_buf = (unsigned*)(w + 16139232);     // 3,600,000 B
    unsigned short* edge_src16 = (unsigned short*)(w + 19739232); // 1,800,000 B

    const int gb = (NROW2 + 3) / 4;                    // gather: 4 waves/block

    // K_A: 3 GEMMs + projections, overlapped with the bin histogram
    gemm_and_count<<<GEMMB + NB3, 256, 0, stream>>>(
        feat_drug, feat_disease, W_ind, b_ind, a_ind,
        W_rev, b_rev, a_rev, W_dd, b_dd, a_dd,
        dst_rev, dst_ind, dst_dd, Wh_all, el_all, er_all, bin_part);

    // K_B: deterministic binned scatter (scan derived in-kernel, no atomics)
    binscat<<<NB3, 256, 0, stream>>>(src_rev, dst_rev, src_ind, dst_ind,
                                     src_dd, dst_dd, bin_part, bin_base,
                                     row_ptr, bin_buf);

    // K_C: per-bin row sort -> row_ptr + final edge_src16
    binsort<<<NBIN, 256, 0, stream>>>(bin_base, bin_buf, row_ptr, edge_src16);

    // K_D: one gather over 40000 merged output rows
    gather_all<<<gb, 256, 0, stream>>>(row_ptr, edge_src16, el_all, er_all,
                                       Wh_all, out);
}